// Round 1
// baseline (4434.247 us; speedup 1.0000x reference)
//
#include <hip/hip_runtime.h>
#include <hip/hip_bf16.h>
#include <cmath>

// Sizes fixed by the problem.
#define B_ 2
#define T_ 1024
#define C_ 1024
#define H_ 16
#define D_ 64          // head dim
#define RT 16          // t-rows per attention block
#define SC 64          // s-chunk length
#define SCALE 0.25f    // 1/sqrt(H)

// ---------------------------------------------------------------------------
// Kernel A: causal attention, one block = (b, h, 16 consecutive t rows).
// Online softmax; V = full x row (1024 ch). Each thread owns (row rr, 64-ch
// chunk cw) -> 64-float accumulator in VGPRs. Output written as bf16 in
// (b, t, h*C + c) concat layout (the A matrix of the final GEMM).
// ---------------------------------------------------------------------------
__global__ __launch_bounds__(256) void attn_kernel(const float* __restrict__ x,
                                                   __hip_bfloat16* __restrict__ O2) {
    __shared__ float qs[RT][D_ + 1];   // +1 pad: break stride-64 bank aliasing
    __shared__ float ks[SC][D_ + 1];
    __shared__ float ls[RT][SC + 1];   // logits -> probs for current chunk
    __shared__ float row_m[RT], row_l[RT], row_alpha[RT];

    const int tid = threadIdx.x;
    const int nTB = T_ / RT;                 // 64 row-tiles per (b,h)
    const int tb = blockIdx.x % nTB;
    const int h  = (blockIdx.x / nTB) % H_;
    const int b  = blockIdx.x / (nTB * H_);
    const int t0 = tb * RT;
    const int rr = tid & 15;                 // row within tile
    const int cw = tid >> 4;                 // 64-channel chunk (0..15)

    const float* xb = x + (size_t)b * T_ * C_;

    // Load Q tile (16 x 64)
#pragma unroll
    for (int i = 0; i < (RT * D_) / 256; ++i) {
        int idx = i * 256 + tid;
        int row = idx >> 6, col = idx & 63;
        qs[row][col] = xb[(size_t)(t0 + row) * C_ + h * D_ + col];
    }
    if (tid < RT) { row_m[tid] = -INFINITY; row_l[tid] = 0.f; }

    float o_acc[64];
#pragma unroll
    for (int j = 0; j < 64; ++j) o_acc[j] = 0.f;

    const int t_max = t0 + RT - 1;
    for (int s0 = 0; s0 <= t_max; s0 += SC) {   // causal: skip chunks beyond t_max
        __syncthreads();
        // Load K chunk (64 x 64)
#pragma unroll
        for (int i = 0; i < (SC * D_) / 256; ++i) {
            int idx = i * 256 + tid;
            int row = idx >> 6, col = idx & 63;
            ks[row][col] = xb[(size_t)(s0 + row) * C_ + h * D_ + col];
        }
        __syncthreads();
        // Scores: thread computes row rr, 4 s-columns (g*4 .. g*4+3)
        {
            const int g = tid >> 4;
            float a0 = 0, a1 = 0, a2 = 0, a3 = 0;
#pragma unroll
            for (int k = 0; k < D_; ++k) {
                float qv = qs[rr][k];
                a0 += qv * ks[g * 4 + 0][k];
                a1 += qv * ks[g * 4 + 1][k];
                a2 += qv * ks[g * 4 + 2][k];
                a3 += qv * ks[g * 4 + 3][k];
            }
            const int tg = t0 + rr;
            ls[rr][g * 4 + 0] = (s0 + g * 4 + 0 <= tg) ? a0 * SCALE : -INFINITY;
            ls[rr][g * 4 + 1] = (s0 + g * 4 + 1 <= tg) ? a1 * SCALE : -INFINITY;
            ls[rr][g * 4 + 2] = (s0 + g * 4 + 2 <= tg) ? a2 * SCALE : -INFINITY;
            ls[rr][g * 4 + 3] = (s0 + g * 4 + 3 <= tg) ? a3 * SCALE : -INFINITY;
        }
        __syncthreads();
        // Online-softmax row update (one lane per row)
        if (tid < RT) {
            float m_old = row_m[tid];
            float cmax = -INFINITY;
#pragma unroll
            for (int s = 0; s < SC; ++s) cmax = fmaxf(cmax, ls[tid][s]);
            float m_new = fmaxf(m_old, cmax);      // chunk 0 always has a valid s -> no NaN
            float alpha = __expf(m_old - m_new);   // exp(-inf)=0 on first chunk
            float sum = 0.f;
#pragma unroll
            for (int s = 0; s < SC; ++s) {
                float p = __expf(ls[tid][s] - m_new);  // masked -inf -> 0
                ls[tid][s] = p;
                sum += p;
            }
            row_l[tid] = row_l[tid] * alpha + sum;
            row_m[tid] = m_new;
            row_alpha[tid] = alpha;
        }
        __syncthreads();
        // O += P @ V for this chunk (V = raw x rows, this thread's 64 channels)
        {
            float alpha = row_alpha[rr];
#pragma unroll
            for (int j = 0; j < 64; ++j) o_acc[j] *= alpha;
            int sN = min(SC, t_max - s0 + 1);
            const float* vbase = xb + (size_t)s0 * C_ + cw * 64;
            for (int s = 0; s < sN; ++s) {
                float p = ls[rr][s];                 // p==0 where masked for this row
                const float4* vp = (const float4*)(vbase + (size_t)s * C_);
#pragma unroll
                for (int j4 = 0; j4 < 16; ++j4) {
                    float4 v = vp[j4];
                    o_acc[j4 * 4 + 0] += p * v.x;
                    o_acc[j4 * 4 + 1] += p * v.y;
                    o_acc[j4 * 4 + 2] += p * v.z;
                    o_acc[j4 * 4 + 3] += p * v.w;
                }
            }
        }
    }
    // Normalize and store bf16, packed 16B stores
    float inv_l = 1.f / row_l[rr];
    __hip_bfloat16* op = O2 + (size_t)(b * T_ + t0 + rr) * (H_ * C_) + h * C_ + cw * 64;
#pragma unroll
    for (int j8 = 0; j8 < 8; ++j8) {
        union { uint4 v; __hip_bfloat16 h8[8]; } pk;
#pragma unroll
        for (int j = 0; j < 8; ++j) pk.h8[j] = __float2bfloat16(o_acc[j8 * 8 + j] * inv_l);
        *(uint4*)(op + j8 * 8) = pk.v;
    }
}

// ---------------------------------------------------------------------------
// Kernel B: OUT[2048,1024] = O2[2048,16384](bf16) @ W[16384,1024](f32), f32 acc.
// 64x64 block tile, 4x4 per-thread micro-tile, K-tile 32.
// ---------------------------------------------------------------------------
#define GM 2048
#define GN 1024
#define GK 16384
#define TLK 32

__global__ __launch_bounds__(256) void out_gemm(const __hip_bfloat16* __restrict__ A,
                                                const float* __restrict__ W,
                                                float* __restrict__ out) {
    __shared__ float As[64][36];   // [m][k], 36 = 32 + 4 pad (keeps 16B align)
    __shared__ float Bs[TLK][68];  // [k][n], 68 = 64 + 4 pad

    const int tid = threadIdx.x;
    const int bn = blockIdx.x & 15;   // GN/64 = 16
    const int bm = blockIdx.x >> 4;   // GM/64 = 32
    const int m0 = bm * 64, n0 = bn * 64;
    const int tx = tid & 15, ty = tid >> 4;

    float acc[4][4];
#pragma unroll
    for (int i = 0; i < 4; ++i)
#pragma unroll
        for (int j = 0; j < 4; ++j) acc[i][j] = 0.f;

    const int aml = tid >> 2;   // 0..63 (m within tile)
    const int akg = tid & 3;    // 0..3  (8-wide k group)
    const int bkk = tid >> 3;   // 0..31 (k within tile)
    const int bng = tid & 7;    // 0..7  (8-wide n group)

    for (int k0 = 0; k0 < GK; k0 += TLK) {
        __syncthreads();
        // A tile: 64m x 32k bf16, one 16B load per thread, convert to f32
        {
            const __hip_bfloat16* ap = A + (size_t)(m0 + aml) * GK + k0 + akg * 8;
            uint4 raw = *(const uint4*)ap;
            const __hip_bfloat16* a8 = (const __hip_bfloat16*)&raw;
            float f[8];
#pragma unroll
            for (int j = 0; j < 8; ++j) f[j] = __bfloat162float(a8[j]);
            *(float4*)&As[aml][akg * 8]     = make_float4(f[0], f[1], f[2], f[3]);
            *(float4*)&As[aml][akg * 8 + 4] = make_float4(f[4], f[5], f[6], f[7]);
        }
        // B tile: 32k x 64n f32, two 16B loads per thread
        {
            const float* bp = W + (size_t)(k0 + bkk) * GN + n0 + bng * 8;
            float4 v0 = *(const float4*)bp;
            float4 v1 = *(const float4*)(bp + 4);
            *(float4*)&Bs[bkk][bng * 8]     = v0;
            *(float4*)&Bs[bkk][bng * 8 + 4] = v1;
        }
        __syncthreads();
#pragma unroll
        for (int kks = 0; kks < TLK; kks += 4) {
            float a[4][4], bq[4][4];
#pragma unroll
            for (int i = 0; i < 4; ++i)
                *(float4*)&a[i][0] = *(const float4*)&As[ty * 4 + i][kks];
#pragma unroll
            for (int s = 0; s < 4; ++s)
                *(float4*)&bq[s][0] = *(const float4*)&Bs[kks + s][tx * 4];
#pragma unroll
            for (int s = 0; s < 4; ++s)
#pragma unroll
                for (int i = 0; i < 4; ++i) {
                    acc[i][0] += a[i][s] * bq[s][0];
                    acc[i][1] += a[i][s] * bq[s][1];
                    acc[i][2] += a[i][s] * bq[s][2];
                    acc[i][3] += a[i][s] * bq[s][3];
                }
        }
    }
#pragma unroll
    for (int i = 0; i < 4; ++i) {
        float4 v = make_float4(acc[i][0], acc[i][1], acc[i][2], acc[i][3]);
        *(float4*)&out[(size_t)(m0 + ty * 4 + i) * GN + n0 + tx * 4] = v;
    }
}

// ---------------------------------------------------------------------------
extern "C" void kernel_launch(void* const* d_in, const int* in_sizes, int n_in,
                              void* d_out, int out_size, void* d_ws, size_t ws_size,
                              hipStream_t stream) {
    const float* x = (const float*)d_in[0];
    // d_in[1] is the causal mask -- recomputed analytically, not read.
    const float* w = (const float*)d_in[2];
    float* out = (float*)d_out;

    // Workspace: O concat (b, t, h*C+c) as bf16: 2*1024*16*1024*2 = 64 MiB
    __hip_bfloat16* O2 = (__hip_bfloat16*)d_ws;

    attn_kernel<<<B_ * H_ * (T_ / RT), 256, 0, stream>>>(x, O2);
    out_gemm<<<(GM / 64) * (GN / 64), 256, 0, stream>>>(O2, w, out);
}

// Round 2
// 478.850 us; speedup vs baseline: 9.2602x; 9.2602x over previous
//
#include <hip/hip_runtime.h>
#include <hip/hip_bf16.h>

#define B_ 2
#define T_ 1024
#define C_ 1024
#define H_ 16

typedef short bf16x8 __attribute__((ext_vector_type(8)));
typedef float f32x4 __attribute__((ext_vector_type(4)));

__device__ inline short f2bf(float x) {
    union { __hip_bfloat16 h; short s; } u;
    u.h = __float2bfloat16(x);
    return u.s;
}

// ---------------------------------------------------------------------------
// Kernel 1: x (fp32) -> xb (bf16), flat copy. 2M elems, 8/thread.
// ---------------------------------------------------------------------------
__global__ __launch_bounds__(256) void cvt_x(const float* __restrict__ x,
                                             short* __restrict__ xb) {
    int idx = (blockIdx.x * 256 + threadIdx.x) * 8;
    float4 a = *(const float4*)(x + idx);
    float4 b = *(const float4*)(x + idx + 4);
    bf16x8 v;
    v[0] = f2bf(a.x); v[1] = f2bf(a.y); v[2] = f2bf(a.z); v[3] = f2bf(a.w);
    v[4] = f2bf(b.x); v[5] = f2bf(b.y); v[6] = f2bf(b.z); v[7] = f2bf(b.w);
    *(bf16x8*)(xb + idx) = v;
}

// ---------------------------------------------------------------------------
// Kernel 2: ZT[b][h][n][s] = Z^T where Z_{b,h} = x_b @ W_h  (bf16 out).
// Computed as D = (W_h^T) . (x_b^T): A-frag rows = n (out ch), B-frag rows = s,
// K = c (1024). Block: (h, n-tile 128, s-tile 128), BOTH batches.
// 256 thr / 4 waves; wave = (batch, s-half-64): 8 ntiles x 4 stiles = 32 mfma/iter.
// ---------------------------------------------------------------------------
#define ZPAD 40   // shorts per LDS row (32 + 8 pad -> 80B stride, 2-way banks)

__global__ __launch_bounds__(256, 2) void zgemm(const short* __restrict__ xb,
                                                const float* __restrict__ W,
                                                short* __restrict__ ZT) {
    __shared__ short Wt[128 * ZPAD];      // [n][c] transposed W tile (bf16)
    __shared__ short Xs[2][128 * ZPAD];   // [b][s][c] x tiles (bf16)

    const int tid = threadIdx.x;
    const int bs = blockIdx.x & 7;
    const int bn = (blockIdx.x >> 3) & 7;
    const int h  = blockIdx.x >> 6;
    const int s0 = bs * 128, n0 = bn * 128;
    const int lane = tid & 63, q = lane >> 4, l16 = lane & 15;
    const int w = tid >> 6, bw = w >> 1, sh = w & 1;

    f32x4 acc[8][4];
#pragma unroll
    for (int i = 0; i < 8; ++i)
#pragma unroll
        for (int j = 0; j < 4; ++j) acc[i][j] = (f32x4){0.f, 0.f, 0.f, 0.f};

    for (int k0 = 0; k0 < 1024; k0 += 32) {
        __syncthreads();
        // Stage W tile transposed into Wt[n][c], converting fp32->bf16.
        // Thread: 2 rounds x (2 consecutive c rows) x (4 n values strided 32).
#pragma unroll
        for (int r = 0; r < 2; ++r) {
            const int c2 = ((tid >> 5) << 1) + (r << 4);     // even c
            const float* w0p = W + (size_t)(h * 1024 + k0 + c2) * 1024 + n0;
            const float* w1p = w0p + 1024;
#pragma unroll
            for (int i = 0; i < 4; ++i) {
                const int n = (tid & 31) + (i << 5);
                float wa = w0p[n], wb = w1p[n];
                unsigned u = (unsigned)(unsigned short)f2bf(wa) |
                             ((unsigned)(unsigned short)f2bf(wb) << 16);
                *(unsigned*)&Wt[n * ZPAD + c2] = u;
            }
        }
        // Stage x tiles (both batches), row-major [s][c], straight 16B copies.
#pragma unroll
        for (int i = 0; i < 4; ++i) {
            const int id = tid + (i << 8);
            const int b2 = id >> 9, s = (id >> 2) & 127, cg = id & 3;
            bf16x8 v = *(const bf16x8*)(xb + (size_t)b2 * (T_ * C_) +
                                        (size_t)(s0 + s) * 1024 + k0 + cg * 8);
            *(bf16x8*)&Xs[b2][s * ZPAD + cg * 8] = v;
        }
        __syncthreads();

        bf16x8 af[8], bfr[4];
#pragma unroll
        for (int nt = 0; nt < 8; ++nt)
            af[nt] = *(bf16x8*)&Wt[(nt * 16 + l16) * ZPAD + q * 8];
#pragma unroll
        for (int st = 0; st < 4; ++st)
            bfr[st] = *(bf16x8*)&Xs[bw][(sh * 64 + st * 16 + l16) * ZPAD + q * 8];
#pragma unroll
        for (int nt = 0; nt < 8; ++nt)
#pragma unroll
            for (int st = 0; st < 4; ++st)
                acc[nt][st] = __builtin_amdgcn_mfma_f32_16x16x32_bf16(
                    af[nt], bfr[st], acc[nt][st], 0, 0, 0);
    }

    // Epilogue: C-layout row = n (quad*4+reg), col = s (l16). Store bf16.
    short* zb = ZT + (size_t)(bw * 16 + h) * (1024 * 1024);
#pragma unroll
    for (int nt = 0; nt < 8; ++nt)
#pragma unroll
        for (int st = 0; st < 4; ++st)
#pragma unroll
            for (int r = 0; r < 4; ++r) {
                int n_abs = n0 + nt * 16 + q * 4 + r;
                int s_abs = s0 + sh * 64 + st * 16 + l16;
                zb[(size_t)n_abs * 1024 + s_abs] = f2bf(acc[nt][st][r]);
            }
}

// ---------------------------------------------------------------------------
// Kernel 3: flash attention + head-sum. Block = (b, h, 32 t-rows).
// Wave w owns out channels [256w, 256w+256). QK^T + P.Z via MFMA.
// Diagonal chunk first -> rescale branch almost always skipped afterwards.
// out += P_h @ ZT_h^T via fp32 atomicAdd (out pre-zeroed).
// ---------------------------------------------------------------------------
__global__ __launch_bounds__(256, 2) void attn(const short* __restrict__ xb,
                                               const short* __restrict__ ZT,
                                               float* __restrict__ out) {
    __shared__ float Sb[32][68];    // scores (fp32), pad 4
    __shared__ short Pb[32][72];    // probs (bf16), pad 8 (144B rows)
    __shared__ float row_m[32], row_l[32], row_al[32];
    __shared__ int flagbuf[2];

    const int tid = threadIdx.x;
    const int tb = blockIdx.x & 31;
    const int h  = (blockIdx.x >> 5) & 15;
    const int b  = blockIdx.x >> 9;
    const int t0 = tb * 32;
    const int lane = tid & 63, q = lane >> 4, l16 = lane & 15;
    const int w = tid >> 6, nw = w * 256;
    const int mw = w & 1, sb0 = (w >> 1) * 2;   // this wave's S tiles

    const short* xbb = xb + (size_t)b * (T_ * C_);
    const short* ztb = ZT + (size_t)(b * 16 + h) * (1024 * 1024);

    // Q fragments (A-operand): rows t0+mw*16+l16, k = head channel.
    bf16x8 qf[2];
#pragma unroll
    for (int ks = 0; ks < 2; ++ks)
        qf[ks] = *(const bf16x8*)(xbb + (size_t)(t0 + mw * 16 + l16) * 1024 +
                                  h * 64 + ks * 32 + q * 8);

    f32x4 acc[2][16];
#pragma unroll
    for (int mt = 0; mt < 2; ++mt)
#pragma unroll
        for (int nt = 0; nt < 16; ++nt) acc[mt][nt] = (f32x4){0.f, 0.f, 0.f, 0.f};

    if (tid < 32) { row_m[tid] = -3.0e38f; row_l[tid] = 0.f; }
    if (tid < 2) flagbuf[tid] = 0;
    __syncthreads();

    const int s0d = t0 & ~63;            // chunk containing the diagonal
    const int nch = (s0d >> 6) + 1;
    for (int ci = 0; ci < nch; ++ci) {
        const int s0 = (ci == 0) ? s0d : (ci - 1) * 64;

        // S = Q K^T for this wave's 2 tiles (K-frags direct from global bf16).
        f32x4 sf[2];
        sf[0] = (f32x4){0.f, 0.f, 0.f, 0.f};
        sf[1] = (f32x4){0.f, 0.f, 0.f, 0.f};
#pragma unroll
        for (int st = 0; st < 2; ++st)
#pragma unroll
            for (int ks = 0; ks < 2; ++ks) {
                bf16x8 kf = *(const bf16x8*)(xbb +
                    (size_t)(s0 + (sb0 + st) * 16 + l16) * 1024 +
                    h * 64 + ks * 32 + q * 8);
                sf[st] = __builtin_amdgcn_mfma_f32_16x16x32_bf16(qf[ks], kf, sf[st], 0, 0, 0);
            }
        __syncthreads();   // prev iteration's Pb/Sb readers done
#pragma unroll
        for (int st = 0; st < 2; ++st)
#pragma unroll
            for (int r = 0; r < 4; ++r)
                Sb[mw * 16 + q * 4 + r][(sb0 + st) * 16 + l16] = sf[st][r];
        __syncthreads();

        // Online softmax: 8 threads per row.
        {
            const int row = tid >> 3, sub = tid & 7;
            float4 v0 = *(float4*)&Sb[row][sub * 8];
            float4 v1 = *(float4*)&Sb[row][sub * 8 + 4];
            float lg[8] = {v0.x, v0.y, v0.z, v0.w, v1.x, v1.y, v1.z, v1.w};
#pragma unroll
            for (int j = 0; j < 8; ++j) lg[j] *= 0.25f;   // scale by 1/sqrt(H)
            if (ci == 0) {                                // causal mask (diag chunk only)
#pragma unroll
                for (int j = 0; j < 8; ++j)
                    if (s0 + sub * 8 + j > t0 + row) lg[j] = -3.0e38f;
            }
            float cm = lg[0];
#pragma unroll
            for (int j = 1; j < 8; ++j) cm = fmaxf(cm, lg[j]);
            cm = fmaxf(cm, __shfl_xor(cm, 1));
            cm = fmaxf(cm, __shfl_xor(cm, 2));
            cm = fmaxf(cm, __shfl_xor(cm, 4));
            float m_old = row_m[row];
            float m_new = fmaxf(m_old, cm);
            float sum = 0.f;
            bf16x8 pv;
#pragma unroll
            for (int j = 0; j < 8; ++j) {
                float p = __expf(lg[j] - m_new);
                sum += p;
                pv[j] = f2bf(p);
            }
            *(bf16x8*)&Pb[row][sub * 8] = pv;
            sum += __shfl_xor(sum, 1);
            sum += __shfl_xor(sum, 2);
            sum += __shfl_xor(sum, 4);
            if (sub == 0) {
                float al = __expf(m_old - m_new);
                row_al[row] = al;
                row_l[row] = row_l[row] * al + sum;
                row_m[row] = m_new;
                if (m_new > m_old) flagbuf[ci & 1] = 1;
            }
            if (tid == 0) flagbuf[(ci + 1) & 1] = 0;  // pre-clear next slot
        }
        __syncthreads();

        // Rescale O only if some row's max moved (rare after diag chunk).
        if (flagbuf[ci & 1]) {
#pragma unroll
            for (int mt = 0; mt < 2; ++mt) {
                float a0 = row_al[mt * 16 + q * 4 + 0];
                float a1 = row_al[mt * 16 + q * 4 + 1];
                float a2 = row_al[mt * 16 + q * 4 + 2];
                float a3 = row_al[mt * 16 + q * 4 + 3];
#pragma unroll
                for (int nt = 0; nt < 16; ++nt) {
                    acc[mt][nt][0] *= a0;
                    acc[mt][nt][1] *= a1;
                    acc[mt][nt][2] *= a2;
                    acc[mt][nt][3] *= a3;
                }
            }
        }

        // P fragments (A-operand) from LDS.
        bf16x8 pf[2][2];
#pragma unroll
        for (int mt = 0; mt < 2; ++mt)
#pragma unroll
            for (int ks = 0; ks < 2; ++ks)
                pf[mt][ks] = *(bf16x8*)&Pb[mt * 16 + l16][ks * 32 + q * 8];

        // O += P @ Z ; Z^T-frags (B-operand) direct from global (L2-hot).
#pragma unroll
        for (int nt = 0; nt < 16; ++nt)
#pragma unroll
            for (int ks = 0; ks < 2; ++ks) {
                bf16x8 vf = *(const bf16x8*)(ztb +
                    (size_t)(nw + nt * 16 + l16) * 1024 + s0 + ks * 32 + q * 8);
                acc[0][nt] = __builtin_amdgcn_mfma_f32_16x16x32_bf16(pf[0][ks], vf, acc[0][nt], 0, 0, 0);
                acc[1][nt] = __builtin_amdgcn_mfma_f32_16x16x32_bf16(pf[1][ks], vf, acc[1][nt], 0, 0, 0);
            }
    }

    // Epilogue: normalize rows, head-sum into out via atomicAdd.
    float invl[2][4];
#pragma unroll
    for (int mt = 0; mt < 2; ++mt)
#pragma unroll
        for (int r = 0; r < 4; ++r)
            invl[mt][r] = 1.f / row_l[mt * 16 + q * 4 + r];
#pragma unroll
    for (int mt = 0; mt < 2; ++mt)
#pragma unroll
        for (int nt = 0; nt < 16; ++nt)
#pragma unroll
            for (int r = 0; r < 4; ++r) {
                size_t idx = (size_t)(b * 1024 + t0 + mt * 16 + q * 4 + r) * 1024 +
                             nw + nt * 16 + l16;
                atomicAdd(out + idx, acc[mt][nt][r] * invl[mt][r]);
            }
}

// ---------------------------------------------------------------------------
extern "C" void kernel_launch(void* const* d_in, const int* in_sizes, int n_in,
                              void* d_out, int out_size, void* d_ws, size_t ws_size,
                              hipStream_t stream) {
    const float* x = (const float*)d_in[0];
    // d_in[1] (mask) recomputed analytically.
    const float* W = (const float*)d_in[2];
    float* out = (float*)d_out;

    short* xb = (short*)d_ws;                          // 4 MiB bf16 x
    short* ZT = (short*)d_ws + (size_t)B_ * T_ * C_;   // 64 MiB bf16 Z^T

    hipMemsetAsync(d_out, 0, (size_t)B_ * T_ * C_ * sizeof(float), stream);
    cvt_x<<<(B_ * T_ * C_) / (256 * 8), 256, 0, stream>>>(x, xb);
    zgemm<<<H_ * 8 * 8, 256, 0, stream>>>(xb, W, ZT);
    attn<<<B_ * H_ * (T_ / 32), 256, 0, stream>>>(xb, ZT, out);
}

// Round 3
// 404.776 us; speedup vs baseline: 10.9548x; 1.1830x over previous
//
#include <hip/hip_runtime.h>
#include <hip/hip_bf16.h>

#define B_ 2
#define T_ 1024
#define C_ 1024
#define H_ 16

typedef short bf16x8 __attribute__((ext_vector_type(8)));
typedef float f32x4 __attribute__((ext_vector_type(4)));

#define MFMA16(a, b, c) __builtin_amdgcn_mfma_f32_16x16x32_bf16(a, b, c, 0, 0, 0)

__device__ inline short f2bf(float x) {
    union { __hip_bfloat16 h; short s; } u;
    u.h = __float2bfloat16(x);
    return u.s;
}

__device__ inline void gl_lds16(const void* g, void* l) {
    __builtin_amdgcn_global_load_lds(
        (const __attribute__((address_space(1))) unsigned int*)g,
        (__attribute__((address_space(3))) unsigned int*)l, 16, 0, 0);
}

// ---------------------------------------------------------------------------
// Kernel: x (fp32) -> xb (bf16), flat. 2M elems, 8/thread.
// ---------------------------------------------------------------------------
__global__ __launch_bounds__(256) void cvt_x(const float* __restrict__ x,
                                             short* __restrict__ xb) {
    int idx = (blockIdx.x * 256 + threadIdx.x) * 8;
    float4 a = *(const float4*)(x + idx);
    float4 b = *(const float4*)(x + idx + 4);
    bf16x8 v;
    v[0] = f2bf(a.x); v[1] = f2bf(a.y); v[2] = f2bf(a.z); v[3] = f2bf(a.w);
    v[4] = f2bf(b.x); v[5] = f2bf(b.y); v[6] = f2bf(b.z); v[7] = f2bf(b.w);
    *(bf16x8*)(xb + idx) = v;
}

// ---------------------------------------------------------------------------
// Kernel: Wt[h][n][c] = bf16(W[h*1024+c][n]) — one-time transpose+convert.
// 64x64 tiles via LDS. Grid = 16h * 16c * 16n.
// ---------------------------------------------------------------------------
__global__ __launch_bounds__(256) void cvt_w(const float* __restrict__ W,
                                             short* __restrict__ Wt) {
    __shared__ float T[64][65];
    const int bid = blockIdx.x;
    const int nb = bid & 15, cb = (bid >> 4) & 15, h = bid >> 8;
    const int t = threadIdx.x;
    const int c0 = cb * 64, n0 = nb * 64;
    const float* src = W + (size_t)(h * 1024 + c0) * 1024 + n0;
    {
        const int cl = t >> 4, nl = (t & 15) * 4;
#pragma unroll
        for (int r = 0; r < 4; ++r) {
            float4 v = *(const float4*)(src + (size_t)(cl + r * 16) * 1024 + nl);
            T[cl + r * 16][nl + 0] = v.x;
            T[cl + r * 16][nl + 1] = v.y;
            T[cl + r * 16][nl + 2] = v.z;
            T[cl + r * 16][nl + 3] = v.w;
        }
    }
    __syncthreads();
    {
        short* dst = Wt + (size_t)(h * 1024 + n0) * 1024 + c0;
        const int nl = t >> 3, cl8 = (t & 7) * 8;
#pragma unroll
        for (int r = 0; r < 2; ++r) {
            const int n = nl + r * 32;
            bf16x8 o;
#pragma unroll
            for (int j = 0; j < 8; ++j) o[j] = f2bf(T[cl8 + j][n]);
            *(bf16x8*)(dst + (size_t)n * 1024 + cl8) = o;
        }
    }
}

// ---------------------------------------------------------------------------
// Kernel: zgemm_fast — ZT[b][h][n][s] = bf16( (x_b @ W_h)^T ).
// D = Wt (A, rows n) x xb^T (B, cols s). 128x128 tile, BK=32, 4 waves 64x64,
// global_load_lds width-16 staging for both operands (m97 structure).
// Grid = 16s(2048) * 16h * 8n ; blockIdx & 7 = n-tile for XCD W-locality.
// ---------------------------------------------------------------------------
__global__ __launch_bounds__(256, 4) void zgemm_fast(const short* __restrict__ xb,
                                                     const short* __restrict__ Wt,
                                                     short* __restrict__ ZT) {
    __shared__ short Al[4][128][8];   // [kgrp][n][8k]  8 KiB
    __shared__ short Bl[4][128][8];   // [kgrp][s][8k]  8 KiB

    const int bid = blockIdx.x;
    const int n_t = bid & 7, h = (bid >> 3) & 15, s_t = bid >> 7;
    const int n0 = n_t * 128, s0g = s_t * 128;     // s over 2048 (b*1024+s)
    const int t = threadIdx.x;
    const int lane = t & 63, q = lane >> 4, l16 = lane & 15;
    const int wv = t >> 6;
    const int wm = (wv & 1) * 64, wn = (wv >> 1) * 64;

    const short* Ab = Wt + ((size_t)h * 1024 + n0) * 1024;
    const short* Bb = xb + (size_t)s0g * 1024;
    const int srow = t & 127, skg = t >> 7;        // staging row / k-group

    char* al_base = (char*)&Al[0][0][0] + (size_t)t * 16;
    char* bl_base = (char*)&Bl[0][0][0] + (size_t)t * 16;

    f32x4 acc[4][4];
#pragma unroll
    for (int i = 0; i < 4; ++i)
#pragma unroll
        for (int j = 0; j < 4; ++j) acc[i][j] = (f32x4){0.f, 0.f, 0.f, 0.f};

    for (int k0 = 0; k0 < 1024; k0 += 32) {
        __syncthreads();
        gl_lds16(Ab + (size_t)srow * 1024 + k0 + skg * 8, al_base);
        gl_lds16(Ab + (size_t)srow * 1024 + k0 + (skg + 2) * 8, al_base + 4096);
        gl_lds16(Bb + (size_t)srow * 1024 + k0 + skg * 8, bl_base);
        gl_lds16(Bb + (size_t)srow * 1024 + k0 + (skg + 2) * 8, bl_base + 4096);
        __syncthreads();
        bf16x8 af[4], bfr[4];
#pragma unroll
        for (int i = 0; i < 4; ++i) af[i] = *(bf16x8*)&Al[q][wm + i * 16 + l16][0];
#pragma unroll
        for (int j = 0; j < 4; ++j) bfr[j] = *(bf16x8*)&Bl[q][wn + j * 16 + l16][0];
#pragma unroll
        for (int i = 0; i < 4; ++i)
#pragma unroll
            for (int j = 0; j < 4; ++j)
                acc[i][j] = MFMA16(af[i], bfr[j], acc[i][j]);
    }

    // Epilogue: row = n, col = s(2048). Whole block is one batch b.
    const int b = s0g >> 10, s_in0 = s0g & 1023;
    short* zb = ZT + ((size_t)(b * 16 + h) << 20);
#pragma unroll
    for (int i = 0; i < 4; ++i)
#pragma unroll
        for (int j = 0; j < 4; ++j)
#pragma unroll
            for (int r = 0; r < 4; ++r) {
                int n = n0 + wm + i * 16 + q * 4 + r;
                int s = s_in0 + wn + j * 16 + l16;
                zb[(size_t)n * 1024 + s] = f2bf(acc[i][j][r]);
            }
}

// ---------------------------------------------------------------------------
// Fallback zgemm (round-2, proven) for small workspace.
// ---------------------------------------------------------------------------
#define ZPAD 40

__global__ __launch_bounds__(256, 2) void zgemm_sm(const short* __restrict__ xb,
                                                   const float* __restrict__ W,
                                                   short* __restrict__ ZT) {
    __shared__ short Wts[128 * ZPAD];
    __shared__ short Xs[2][128 * ZPAD];

    const int tid = threadIdx.x;
    const int bs = blockIdx.x & 7;
    const int bn = (blockIdx.x >> 3) & 7;
    const int h  = blockIdx.x >> 6;
    const int s0 = bs * 128, n0 = bn * 128;
    const int lane = tid & 63, q = lane >> 4, l16 = lane & 15;
    const int w = tid >> 6, bw = w >> 1, sh = w & 1;

    f32x4 acc[8][4];
#pragma unroll
    for (int i = 0; i < 8; ++i)
#pragma unroll
        for (int j = 0; j < 4; ++j) acc[i][j] = (f32x4){0.f, 0.f, 0.f, 0.f};

    for (int k0 = 0; k0 < 1024; k0 += 32) {
        __syncthreads();
#pragma unroll
        for (int r = 0; r < 2; ++r) {
            const int c2 = ((tid >> 5) << 1) + (r << 4);
            const float* w0p = W + (size_t)(h * 1024 + k0 + c2) * 1024 + n0;
            const float* w1p = w0p + 1024;
#pragma unroll
            for (int i = 0; i < 4; ++i) {
                const int n = (tid & 31) + (i << 5);
                float wa = w0p[n], wb = w1p[n];
                unsigned u = (unsigned)(unsigned short)f2bf(wa) |
                             ((unsigned)(unsigned short)f2bf(wb) << 16);
                *(unsigned*)&Wts[n * ZPAD + c2] = u;
            }
        }
#pragma unroll
        for (int i = 0; i < 4; ++i) {
            const int id = tid + (i << 8);
            const int b2 = id >> 9, s = (id >> 2) & 127, cg = id & 3;
            bf16x8 v = *(const bf16x8*)(xb + (size_t)b2 * (T_ * C_) +
                                        (size_t)(s0 + s) * 1024 + k0 + cg * 8);
            *(bf16x8*)&Xs[b2][s * ZPAD + cg * 8] = v;
        }
        __syncthreads();

        bf16x8 af[8], bfr[4];
#pragma unroll
        for (int nt = 0; nt < 8; ++nt)
            af[nt] = *(bf16x8*)&Wts[(nt * 16 + l16) * ZPAD + q * 8];
#pragma unroll
        for (int st = 0; st < 4; ++st)
            bfr[st] = *(bf16x8*)&Xs[bw][(sh * 64 + st * 16 + l16) * ZPAD + q * 8];
#pragma unroll
        for (int nt = 0; nt < 8; ++nt)
#pragma unroll
            for (int st = 0; st < 4; ++st)
                acc[nt][st] = MFMA16(af[nt], bfr[st], acc[nt][st]);
    }

    short* zb = ZT + (size_t)(bw * 16 + h) * (1024 * 1024);
#pragma unroll
    for (int nt = 0; nt < 8; ++nt)
#pragma unroll
        for (int st = 0; st < 4; ++st)
#pragma unroll
            for (int r = 0; r < 4; ++r) {
                int n_abs = n0 + nt * 16 + q * 4 + r;
                int s_abs = s0 + sh * 64 + st * 16 + l16;
                zb[(size_t)n_abs * 1024 + s_abs] = f2bf(acc[nt][st][r]);
            }
}

// ---------------------------------------------------------------------------
// Kernel: attn v2 — 512 threads, 64-row Q-tiles, paired (p, 15-p) for balance.
// In-wave softmax, 1 barrier/chunk, software-pipelined QK(ci+1) || PV(ci).
// Waves 0-3: QK+softmax for row-group (w&3); all 8 waves: PV on disjoint
// 128-channel slices. out += P@Z via fp32 atomics (out pre-zeroed).
// ---------------------------------------------------------------------------
__global__ __launch_bounds__(512, 2) void attn(const short* __restrict__ xb,
                                               const short* __restrict__ ZT,
                                               float* __restrict__ out) {
    __shared__ short Pb[2][64][72];     // probs bf16, double-buffered
    __shared__ float row_al[2][64];
    __shared__ float row_l[64];
    __shared__ int   flags[2][4];

    const int tid = threadIdx.x;
    const int bh = blockIdx.x & 31, p = blockIdx.x >> 5;   // XCD-pinned (b,h)
    const int b = bh >> 4, h = bh & 15;
    const int lane = tid & 63, q = lane >> 4, l16 = lane & 15;
    const int w = tid >> 6;
    const int g = w & 3;          // QK row-group
    const int nw = w * 128;       // PV channel base
    const short* xbb = xb + ((size_t)b << 20);
    const short* ztb = ZT + ((size_t)(b * 16 + h) << 20);

    const int tiles[2] = { p, 15 - p };
    for (int ti = 0; ti < 2; ++ti) {
        const int tb = tiles[ti];
        const int t0 = tb * 64;
        const int nch = tb + 1;

        f32x4 acc[4][8];
#pragma unroll
        for (int mt = 0; mt < 4; ++mt)
#pragma unroll
            for (int nt = 0; nt < 8; ++nt) acc[mt][nt] = (f32x4){0.f, 0.f, 0.f, 0.f};
        float m_r[4], l_r[4];
#pragma unroll
        for (int r = 0; r < 4; ++r) { m_r[r] = -3.0e38f; l_r[r] = 0.f; }

        bf16x8 qf[2];
        if (w < 4) {
#pragma unroll
            for (int ks = 0; ks < 2; ++ks)
                qf[ks] = *(const bf16x8*)(xbb + (size_t)(t0 + g * 16 + l16) * 1024 +
                                          h * 64 + ks * 32 + q * 8);
        }

        for (int ci = -1; ci < nch; ++ci) {
            __syncthreads();
            const int cc = ci + 1;
            if (w < 4 && cc < nch) {
                const int s0 = (cc == 0) ? t0 : (cc - 1) * 64;
                const int par = cc & 1;
                // QK^T
                f32x4 sf[4];
#pragma unroll
                for (int st = 0; st < 4; ++st) sf[st] = (f32x4){0.f, 0.f, 0.f, 0.f};
#pragma unroll
                for (int st = 0; st < 4; ++st)
#pragma unroll
                    for (int ks = 0; ks < 2; ++ks) {
                        bf16x8 kf = *(const bf16x8*)(xbb +
                            (size_t)(s0 + st * 16 + l16) * 1024 + h * 64 + ks * 32 + q * 8);
                        sf[st] = MFMA16(qf[ks], kf, sf[st]);
                    }
                // In-register online softmax (rows q*4+r of group g)
                float mx[4] = {-3.0e38f, -3.0e38f, -3.0e38f, -3.0e38f};
#pragma unroll
                for (int st = 0; st < 4; ++st)
#pragma unroll
                    for (int r = 0; r < 4; ++r) {
                        float v = sf[st][r] * 0.25f;
                        if (cc == 0 && (s0 + st * 16 + l16) > (t0 + g * 16 + q * 4 + r))
                            v = -3.0e38f;
                        sf[st][r] = v;
                        mx[r] = fmaxf(mx[r], v);
                    }
#pragma unroll
                for (int r = 0; r < 4; ++r) {
                    mx[r] = fmaxf(mx[r], __shfl_xor(mx[r], 1));
                    mx[r] = fmaxf(mx[r], __shfl_xor(mx[r], 2));
                    mx[r] = fmaxf(mx[r], __shfl_xor(mx[r], 4));
                    mx[r] = fmaxf(mx[r], __shfl_xor(mx[r], 8));
                }
                float sum[4], al[4];
                int upd = 0;
#pragma unroll
                for (int r = 0; r < 4; ++r) {
                    float m_new = fmaxf(m_r[r], mx[r]);
                    al[r] = __expf(m_r[r] - m_new);
                    upd |= (m_new > m_r[r]) ? 1 : 0;
                    m_r[r] = m_new;
                    sum[r] = 0.f;
                }
#pragma unroll
                for (int st = 0; st < 4; ++st)
#pragma unroll
                    for (int r = 0; r < 4; ++r) {
                        float pv = __expf(sf[st][r] - m_r[r]);
                        sum[r] += pv;
                        Pb[par][g * 16 + q * 4 + r][st * 16 + l16] = f2bf(pv);
                    }
#pragma unroll
                for (int r = 0; r < 4; ++r) {
                    sum[r] += __shfl_xor(sum[r], 1);
                    sum[r] += __shfl_xor(sum[r], 2);
                    sum[r] += __shfl_xor(sum[r], 4);
                    sum[r] += __shfl_xor(sum[r], 8);
                    l_r[r] = l_r[r] * al[r] + sum[r];
                }
                if (l16 == 0) {
#pragma unroll
                    for (int r = 0; r < 4; ++r) row_al[par][g * 16 + q * 4 + r] = al[r];
                }
                int any_upd = __any(upd);
                if (lane == 0) flags[par][g] = any_upd;
            }
            if (ci >= 0) {
                const int par = ci & 1;
                // Rescale accumulators only if some row max moved.
                if (flags[par][0] | flags[par][1] | flags[par][2] | flags[par][3]) {
#pragma unroll
                    for (int mt = 0; mt < 4; ++mt) {
                        float a0 = row_al[par][mt * 16 + q * 4 + 0];
                        float a1 = row_al[par][mt * 16 + q * 4 + 1];
                        float a2 = row_al[par][mt * 16 + q * 4 + 2];
                        float a3 = row_al[par][mt * 16 + q * 4 + 3];
#pragma unroll
                        for (int nt = 0; nt < 8; ++nt) {
                            acc[mt][nt][0] *= a0;
                            acc[mt][nt][1] *= a1;
                            acc[mt][nt][2] *= a2;
                            acc[mt][nt][3] *= a3;
                        }
                    }
                }
                // PV
                bf16x8 pf[4][2];
#pragma unroll
                for (int mt = 0; mt < 4; ++mt)
#pragma unroll
                    for (int ks = 0; ks < 2; ++ks)
                        pf[mt][ks] = *(bf16x8*)&Pb[par][mt * 16 + l16][ks * 32 + q * 8];
                const int s0p = (ci == 0) ? t0 : (ci - 1) * 64;
#pragma unroll
                for (int nt = 0; nt < 8; ++nt)
#pragma unroll
                    for (int ks = 0; ks < 2; ++ks) {
                        bf16x8 vf = *(const bf16x8*)(ztb +
                            (size_t)(nw + nt * 16 + l16) * 1024 + s0p + ks * 32 + q * 8);
#pragma unroll
                        for (int mt = 0; mt < 4; ++mt)
                            acc[mt][nt] = MFMA16(pf[mt][ks], vf, acc[mt][nt]);
                    }
            }
        }

        // Epilogue: share row sums, normalize, head-sum via atomics.
        if (w < 4 && l16 == 0) {
#pragma unroll
            for (int r = 0; r < 4; ++r) row_l[g * 16 + q * 4 + r] = l_r[r];
        }
        __syncthreads();
#pragma unroll
        for (int mt = 0; mt < 4; ++mt) {
            float i0 = 1.f / row_l[mt * 16 + q * 4 + 0];
            float i1 = 1.f / row_l[mt * 16 + q * 4 + 1];
            float i2 = 1.f / row_l[mt * 16 + q * 4 + 2];
            float i3 = 1.f / row_l[mt * 16 + q * 4 + 3];
#pragma unroll
            for (int nt = 0; nt < 8; ++nt) {
                size_t base = (size_t)(b * 1024 + t0 + mt * 16 + q * 4) * 1024 +
                              nw + nt * 16 + l16;
                atomicAdd(out + base,            acc[mt][nt][0] * i0);
                atomicAdd(out + base + 1024,     acc[mt][nt][1] * i1);
                atomicAdd(out + base + 2048,     acc[mt][nt][2] * i2);
                atomicAdd(out + base + 3072,     acc[mt][nt][3] * i3);
            }
        }
        __syncthreads();   // protect Pb/row_l reuse by next tile
    }
}

// ---------------------------------------------------------------------------
extern "C" void kernel_launch(void* const* d_in, const int* in_sizes, int n_in,
                              void* d_out, int out_size, void* d_ws, size_t ws_size,
                              hipStream_t stream) {
    const float* x = (const float*)d_in[0];
    // d_in[1] (mask) recomputed analytically.
    const float* W = (const float*)d_in[2];
    float* out = (float*)d_out;

    short* xb = (short*)d_ws;                              // 4 MiB
    short* ZT = (short*)d_ws + (size_t)B_ * T_ * C_;       // 64 MiB
    short* Wt = ZT + (size_t)B_ * H_ * 1024 * 1024;        // 32 MiB (big path)

    const bool big_ws = ws_size >= (size_t)100 * 1024 * 1024;

    hipMemsetAsync(d_out, 0, (size_t)B_ * T_ * C_ * sizeof(float), stream);
    cvt_x<<<(B_ * T_ * C_) / (256 * 8), 256, 0, stream>>>(x, xb);
    if (big_ws) {
        cvt_w<<<16 * 16 * 16, 256, 0, stream>>>(W, Wt);
        zgemm_fast<<<16 * 16 * 8, 256, 0, stream>>>(xb, Wt, ZT);
    } else {
        zgemm_sm<<<H_ * 8 * 8, 256, 0, stream>>>(xb, W, ZT);
    }
    attn<<<256, 512, 0, stream>>>(xb, ZT, out);
}